// Round 2
// baseline (1069.961 us; speedup 1.0000x reference)
//
#include <hip/hip_runtime.h>

#define NN  20000
#define NE  320000
#define FIN 256
#define FH  512

typedef __attribute__((ext_vector_type(8))) short bf16x8;
typedef __attribute__((ext_vector_type(4))) float f32x4;

static __device__ __forceinline__ unsigned short f2b(float f) {
    union { float f; unsigned int i; } v; v.f = f;
    return (unsigned short)((v.i + 0x7fffu + ((v.i >> 16) & 1u)) >> 16);
}
static __device__ __forceinline__ f32x4 mfma16(bf16x8 a, bf16x8 b, f32x4 c) {
    return __builtin_amdgcn_mfma_f32_16x16x32_bf16(a, b, c, 0, 0, 0);
}

// ------------------------------------------------- transpose + fp32->bf16
// dst[c*R + r] = bf16(src[r*C + c])
__global__ void transpose_f32_bf16(const float* __restrict__ src,
                                   unsigned short* __restrict__ dst, int R, int C) {
    int idx = blockIdx.x * 256 + threadIdx.x;
    if (idx < R * C) {
        int r = idx / C, c = idx - r * C;
        dst[c * R + r] = f2b(src[idx]);
    }
}

// ---------------------------------------------------------------- edge MLP
// per block: 64 edges. Stage X fp32->bf16 LDS; H = relu(X@W1+b1) swizzled LDS;
// E = H@W2+b2; msg = relu(node_feat[src]+E); atomicAdd into out_h[dst].
__global__ void __launch_bounds__(256, 2)
gine_edge(const float* __restrict__ edge_feat,
          const float* __restrict__ node_feat,
          const int* __restrict__ srcI,
          const int* __restrict__ dstI,
          const unsigned short* __restrict__ W1T,   // [512,256] bf16 k-contig
          const float* __restrict__ b1,             // [512]
          const unsigned short* __restrict__ W2T,   // [256,512] bf16 k-contig
          const float* __restrict__ b2,             // [256]
          float* __restrict__ out_h)                // [NN,256] fp32 accum
{
    __shared__ union {
        unsigned short Xs[64 * 264];   // staged bf16 input, +8 pad
        unsigned short Hs[64 * 512];   // XOR-swizzled hidden (aliases Xs)
    } sh;

    const int tid  = threadIdx.x;
    const int wave = tid >> 6;
    const int lane = tid & 63;
    const int quad = lane >> 4;
    const int ln   = lane & 15;
    const int e0   = blockIdx.x * 64;

    // ---- stage edge_feat tile -> bf16 LDS (coalesced f32x4 pairs)
    #pragma unroll
    for (int it = 0; it < 8; ++it) {
        const int chunk = tid + it * 256;          // 2048 chunks of 8 elems
        const int row = chunk >> 5;
        const int c8  = (chunk & 31) << 3;
        const float* p = edge_feat + (size_t)(e0 + row) * FIN + c8;
        f32x4 o0 = *(const f32x4*)(p);
        f32x4 o1 = *(const f32x4*)(p + 4);
        bf16x8 pack;
        #pragma unroll
        for (int j = 0; j < 4; ++j) {
            pack[j]     = (short)f2b(o0[j]);
            pack[j + 4] = (short)f2b(o1[j]);
        }
        *(bf16x8*)(&sh.Xs[row * 264 + c8]) = pack;
    }
    __syncthreads();

    // ---- layer 1: M=64, N=512, K=256; wave owns 8 col-tiles, 4 row-tiles
    f32x4 zero4 = {0.f, 0.f, 0.f, 0.f};
    f32x4 acc1[4][8];
    #pragma unroll
    for (int rt = 0; rt < 4; ++rt)
        #pragma unroll
        for (int cw = 0; cw < 8; ++cw) acc1[rt][cw] = zero4;

    const unsigned short* bB = W1T + (wave * 128 + ln) * FIN + quad * 8;
    #pragma unroll
    for (int ks = 0; ks < 8; ++ks) {
        bf16x8 a[4], b[8];
        #pragma unroll
        for (int rt = 0; rt < 4; ++rt)
            a[rt] = *(const bf16x8*)(&sh.Xs[(rt * 16 + ln) * 264 + quad * 8 + ks * 32]);
        #pragma unroll
        for (int cw = 0; cw < 8; ++cw)
            b[cw] = *(const bf16x8*)(bB + cw * 16 * FIN + ks * 32);
        #pragma unroll
        for (int rt = 0; rt < 4; ++rt)
            #pragma unroll
            for (int cw = 0; cw < 8; ++cw)
                acc1[rt][cw] = mfma16(a[rt], b[cw], acc1[rt][cw]);
    }
    __syncthreads();   // done reading Xs before overwriting aliased Hs

    // bias + relu -> bf16 -> swizzled LDS  (C layout: col=ln, row=quad*4+r)
    #pragma unroll
    for (int cw = 0; cw < 8; ++cw) {
        const int n = wave * 128 + cw * 16 + ln;   // hidden col = layer-2 k
        const float bias = b1[n];
        #pragma unroll
        for (int rt = 0; rt < 4; ++rt)
            #pragma unroll
            for (int r = 0; r < 4; ++r) {
                const int row = rt * 16 + quad * 4 + r;
                const float v = fmaxf(acc1[rt][cw][r] + bias, 0.f);
                sh.Hs[(row << 9) + (((n >> 3) ^ (row & 7)) << 3) + (n & 7)] = f2b(v);
            }
    }
    __syncthreads();

    // ---- layer 2: M=64, N=256, K=512; wave owns 4 col-tiles
    f32x4 acc2[4][4];
    #pragma unroll
    for (int rt = 0; rt < 4; ++rt)
        #pragma unroll
        for (int cw = 0; cw < 4; ++cw) acc2[rt][cw] = zero4;

    #pragma unroll
    for (int ks = 0; ks < 16; ++ks) {
        const int kb = ks * 4 + quad;
        bf16x8 a[4], b[4];
        #pragma unroll
        for (int rt = 0; rt < 4; ++rt) {
            const int row = rt * 16 + ln;
            a[rt] = *(const bf16x8*)(&sh.Hs[(row << 9) + (((kb ^ (row & 7)) << 3))]);
        }
        #pragma unroll
        for (int cw = 0; cw < 4; ++cw)
            b[cw] = *(const bf16x8*)(W2T + (wave * 64 + cw * 16 + ln) * FH + kb * 8);
        #pragma unroll
        for (int rt = 0; rt < 4; ++rt)
            #pragma unroll
            for (int cw = 0; cw < 4; ++cw)
                acc2[rt][cw] = mfma16(a[rt], b[cw], acc2[rt][cw]);
    }

    // ---- epilogue: gather + relu + atomic scatter-add (all fp32)
    float biasv[4];
    #pragma unroll
    for (int cw = 0; cw < 4; ++cw)
        biasv[cw] = b2[wave * 64 + cw * 16 + ln];
    #pragma unroll
    for (int rt = 0; rt < 4; ++rt)
        #pragma unroll
        for (int r = 0; r < 4; ++r) {
            const int row = rt * 16 + quad * 4 + r;
            const int sn = srcI[e0 + row];
            const int dn = dstI[e0 + row];
            const float* nf = node_feat + (size_t)sn * FIN + wave * 64 + ln;
            float* oh = out_h + (size_t)dn * FIN + wave * 64 + ln;
            #pragma unroll
            for (int cw = 0; cw < 4; ++cw) {
                const float e = acc2[rt][cw][r] + biasv[cw];
                const float msg = fmaxf(nf[cw * 16] + e, 0.f);
                atomicAdd(oh + cw * 16, msg);
            }
        }
}

// ---------------------------------------------------------------- node MLP
__global__ void __launch_bounds__(256, 2)
gine_node(const float* __restrict__ node_feat,
          const float* __restrict__ out_h,
          const unsigned short* __restrict__ W1T,   // [512,256] bf16
          const float* __restrict__ b1,
          const unsigned short* __restrict__ W2T,   // [256,512] bf16
          const float* __restrict__ b2,
          const float* __restrict__ eps,
          float* __restrict__ out)
{
    __shared__ union {
        unsigned short Xs[64 * 264];
        unsigned short Hs[64 * 512];
    } sh;

    const int tid  = threadIdx.x;
    const int wave = tid >> 6;
    const int lane = tid & 63;
    const int quad = lane >> 4;
    const int ln   = lane & 15;
    const int n0   = blockIdx.x * 64;
    const float epsv = 1.0f + eps[0];

    // stage x = (1+eps)*node_feat + out_h  -> bf16 LDS
    #pragma unroll
    for (int it = 0; it < 8; ++it) {
        const int chunk = tid + it * 256;
        const int row = chunk >> 5;
        const int c8  = (chunk & 31) << 3;
        const int g   = n0 + row;
        bf16x8 pack = {0, 0, 0, 0, 0, 0, 0, 0};
        if (g < NN) {
            const float* pn = node_feat + (size_t)g * FIN + c8;
            const float* ph = out_h + (size_t)g * FIN + c8;
            f32x4 n0v = *(const f32x4*)(pn);
            f32x4 n1v = *(const f32x4*)(pn + 4);
            f32x4 h0v = *(const f32x4*)(ph);
            f32x4 h1v = *(const f32x4*)(ph + 4);
            #pragma unroll
            for (int j = 0; j < 4; ++j) {
                pack[j]     = (short)f2b(epsv * n0v[j] + h0v[j]);
                pack[j + 4] = (short)f2b(epsv * n1v[j] + h1v[j]);
            }
        }
        *(bf16x8*)(&sh.Xs[row * 264 + c8]) = pack;
    }
    __syncthreads();

    // ---- layer 1
    f32x4 zero4 = {0.f, 0.f, 0.f, 0.f};
    f32x4 acc1[4][8];
    #pragma unroll
    for (int rt = 0; rt < 4; ++rt)
        #pragma unroll
        for (int cw = 0; cw < 8; ++cw) acc1[rt][cw] = zero4;

    const unsigned short* bB = W1T + (wave * 128 + ln) * FIN + quad * 8;
    #pragma unroll
    for (int ks = 0; ks < 8; ++ks) {
        bf16x8 a[4], b[8];
        #pragma unroll
        for (int rt = 0; rt < 4; ++rt)
            a[rt] = *(const bf16x8*)(&sh.Xs[(rt * 16 + ln) * 264 + quad * 8 + ks * 32]);
        #pragma unroll
        for (int cw = 0; cw < 8; ++cw)
            b[cw] = *(const bf16x8*)(bB + cw * 16 * FIN + ks * 32);
        #pragma unroll
        for (int rt = 0; rt < 4; ++rt)
            #pragma unroll
            for (int cw = 0; cw < 8; ++cw)
                acc1[rt][cw] = mfma16(a[rt], b[cw], acc1[rt][cw]);
    }
    __syncthreads();

    #pragma unroll
    for (int cw = 0; cw < 8; ++cw) {
        const int n = wave * 128 + cw * 16 + ln;
        const float bias = b1[n];
        #pragma unroll
        for (int rt = 0; rt < 4; ++rt)
            #pragma unroll
            for (int r = 0; r < 4; ++r) {
                const int row = rt * 16 + quad * 4 + r;
                const float v = fmaxf(acc1[rt][cw][r] + bias, 0.f);
                sh.Hs[(row << 9) + (((n >> 3) ^ (row & 7)) << 3) + (n & 7)] = f2b(v);
            }
    }
    __syncthreads();

    // ---- layer 2
    f32x4 acc2[4][4];
    #pragma unroll
    for (int rt = 0; rt < 4; ++rt)
        #pragma unroll
        for (int cw = 0; cw < 4; ++cw) acc2[rt][cw] = zero4;

    #pragma unroll
    for (int ks = 0; ks < 16; ++ks) {
        const int kb = ks * 4 + quad;
        bf16x8 a[4], b[4];
        #pragma unroll
        for (int rt = 0; rt < 4; ++rt) {
            const int row = rt * 16 + ln;
            a[rt] = *(const bf16x8*)(&sh.Hs[(row << 9) + (((kb ^ (row & 7)) << 3))]);
        }
        #pragma unroll
        for (int cw = 0; cw < 4; ++cw)
            b[cw] = *(const bf16x8*)(W2T + (wave * 64 + cw * 16 + ln) * FH + kb * 8);
        #pragma unroll
        for (int rt = 0; rt < 4; ++rt)
            #pragma unroll
            for (int cw = 0; cw < 4; ++cw)
                acc2[rt][cw] = mfma16(a[rt], b[cw], acc2[rt][cw]);
    }

    float biasv[4];
    #pragma unroll
    for (int cw = 0; cw < 4; ++cw)
        biasv[cw] = b2[wave * 64 + cw * 16 + ln];
    #pragma unroll
    for (int rt = 0; rt < 4; ++rt)
        #pragma unroll
        for (int r = 0; r < 4; ++r) {
            const int row = rt * 16 + quad * 4 + r;
            const int g = n0 + row;
            if (g < NN) {
                #pragma unroll
                for (int cw = 0; cw < 4; ++cw)
                    out[(size_t)g * FIN + wave * 64 + cw * 16 + ln] =
                        acc2[rt][cw][r] + biasv[cw];
            }
        }
}

// ---------------------------------------------------------------- launch
extern "C" void kernel_launch(void* const* d_in, const int* in_sizes, int n_in,
                              void* d_out, int out_size, void* d_ws, size_t ws_size,
                              hipStream_t stream) {
    const float* node_feat = (const float*)d_in[0];
    const float* edge_feat = (const float*)d_in[1];
    const int* srcI = (const int*)d_in[2];
    const int* dstI = (const int*)d_in[3];
    const float* We1 = (const float*)d_in[4];
    const float* be1 = (const float*)d_in[5];
    const float* We2 = (const float*)d_in[6];
    const float* be2 = (const float*)d_in[7];
    const float* Wn1 = (const float*)d_in[8];
    const float* bn1 = (const float*)d_in[9];
    const float* Wn2 = (const float*)d_in[10];
    const float* bn2 = (const float*)d_in[11];
    const float* eps = (const float*)d_in[12];

    char* ws = (char*)d_ws;
    float* out_h = (float*)ws;                                  // 20,480,000 B
    unsigned short* W1T  = (unsigned short*)(ws + 20480000);    // 256 KB each
    unsigned short* W2T  = W1T + 131072;
    unsigned short* Wn1T = W2T + 131072;
    unsigned short* Wn2T = Wn1T + 131072;

    hipMemsetAsync(out_h, 0, (size_t)NN * FIN * sizeof(float), stream);
    transpose_f32_bf16<<<512, 256, 0, stream>>>(We1, W1T, FIN, FH);
    transpose_f32_bf16<<<512, 256, 0, stream>>>(We2, W2T, FH, FIN);
    transpose_f32_bf16<<<512, 256, 0, stream>>>(Wn1, Wn1T, FIN, FH);
    transpose_f32_bf16<<<512, 256, 0, stream>>>(Wn2, Wn2T, FH, FIN);

    gine_edge<<<NE / 64, 256, 0, stream>>>(edge_feat, node_feat, srcI, dstI,
                                           W1T, be1, W2T, be2, out_h);
    gine_node<<<(NN + 63) / 64, 256, 0, stream>>>(node_feat, out_h, Wn1T, bn1,
                                                  Wn2T, bn2, eps, (float*)d_out);
}

// Round 3
// 950.227 us; speedup vs baseline: 1.1260x; 1.1260x over previous
//
#include <hip/hip_runtime.h>

#define NN  20000
#define NE  320000
#define FIN 256
#define FH  512

typedef __attribute__((ext_vector_type(8))) short bf16x8;
typedef __attribute__((ext_vector_type(4))) float f32x4;

static __device__ __forceinline__ unsigned short f2b(float f) {
    union { float f; unsigned int i; } v; v.f = f;
    return (unsigned short)((v.i + 0x7fffu + ((v.i >> 16) & 1u)) >> 16);
}
static __device__ __forceinline__ f32x4 mfma16(bf16x8 a, bf16x8 b, f32x4 c) {
    return __builtin_amdgcn_mfma_f32_16x16x32_bf16(a, b, c, 0, 0, 0);
}

// ------------------------------------------------- transpose + fp32->bf16
// dst[c*R + r] = bf16(src[r*C + c]); R,C multiples of 32. Tiled, coalesced.
__global__ void transpose_f32_bf16(const float* __restrict__ src,
                                   unsigned short* __restrict__ dst, int R, int C) {
    __shared__ unsigned short t[32][33];
    const int tx  = threadIdx.x & 31;
    const int tyb = threadIdx.x >> 5;          // 0..7, 4 rows each
    const int bx = blockIdx.x % (C >> 5);
    const int by = blockIdx.x / (C >> 5);
    #pragma unroll
    for (int j = 0; j < 4; ++j) {
        const int row = by * 32 + tyb * 4 + j;
        t[tyb * 4 + j][tx] = f2b(src[(size_t)row * C + bx * 32 + tx]);
    }
    __syncthreads();
    #pragma unroll
    for (int j = 0; j < 4; ++j) {
        const int c = bx * 32 + tyb * 4 + j;
        dst[(size_t)c * R + by * 32 + tx] = t[tx][tyb * 4 + j];
    }
}

// ------------------------------------------------- sort-by-dst prep
__global__ void hist_dst(const int* __restrict__ dstI, int* __restrict__ cnt) {
    int e = blockIdx.x * 256 + threadIdx.x;
    if (e < NE) atomicAdd(&cnt[dstI[e]], 1);
}

// single block, 1024 threads: exclusive prefix sum of cnt[NN] -> cursor[NN]
__global__ void scan_excl(const int* __restrict__ cnt, int* __restrict__ cursor) {
    __shared__ int s[1024];
    const int t = threadIdx.x;
    const int lo = t * 20;
    const int hi = (lo + 20 < NN) ? lo + 20 : NN;
    int sum = 0;
    for (int i = lo; i < hi; ++i) sum += cnt[i];
    s[t] = sum;
    __syncthreads();
    // Hillis-Steele inclusive scan over the 1024 per-thread sums
    for (int off = 1; off < 1024; off <<= 1) {
        int v = (t >= off) ? s[t - off] : 0;
        __syncthreads();
        s[t] += v;
        __syncthreads();
    }
    int base = (t > 0) ? s[t - 1] : 0;   // exclusive prefix of this segment
    for (int i = lo; i < hi; ++i) { cursor[i] = base; base += cnt[i]; }
}

__global__ void scatter_perm(const int* __restrict__ dstI,
                             int* __restrict__ cursor, int* __restrict__ perm) {
    int e = blockIdx.x * 256 + threadIdx.x;
    if (e < NE) {
        int pos = atomicAdd(&cursor[dstI[e]], 1);
        perm[pos] = e;
    }
}

// ---------------------------------------------------------------- edge MLP
// per block: 64 dst-sorted edges (via perm). Stage X fp32->bf16 LDS;
// H = relu(X@W1+b1) swizzled LDS; E = H@W2+b2;
// msg = relu(node_feat[src]+E) -> LDS; per-column run-length reduce over the
// sorted dst rows -> ~5 atomics per column per block instead of 64.
__global__ void __launch_bounds__(256, 2)
gine_edge(const float* __restrict__ edge_feat,
          const float* __restrict__ node_feat,
          const int* __restrict__ srcI,
          const int* __restrict__ dstI,
          const int* __restrict__ perm,
          const unsigned short* __restrict__ W1T,   // [512,256] bf16 k-contig
          const float* __restrict__ b1,             // [512]
          const unsigned short* __restrict__ W2T,   // [256,512] bf16 k-contig
          const float* __restrict__ b2,             // [256]
          float* __restrict__ out_h)                // [NN,256] fp32 accum
{
    __shared__ union {
        unsigned short Xs[64 * 264];   // staged bf16 input, +8 pad
        unsigned short Hs[64 * 512];   // XOR-swizzled hidden
        float          Msg[64 * 260];  // fp32 messages, +4 pad
    } sh;
    __shared__ int snS[64], dnS[64], eS[64];

    const int tid  = threadIdx.x;
    const int wave = tid >> 6;
    const int lane = tid & 63;
    const int quad = lane >> 4;
    const int ln   = lane & 15;
    const int e0   = blockIdx.x * 64;

    if (tid < 64) {
        const int e = perm[e0 + tid];
        eS[tid]  = e;
        snS[tid] = srcI[e];
        dnS[tid] = dstI[e];
    }
    __syncthreads();

    // ---- stage gathered edge_feat rows -> bf16 LDS
    #pragma unroll
    for (int it = 0; it < 8; ++it) {
        const int chunk = tid + it * 256;          // 2048 chunks of 8 elems
        const int row = chunk >> 5;
        const int c8  = (chunk & 31) << 3;
        const float* p = edge_feat + (size_t)eS[row] * FIN + c8;
        f32x4 o0 = *(const f32x4*)(p);
        f32x4 o1 = *(const f32x4*)(p + 4);
        bf16x8 pack;
        #pragma unroll
        for (int j = 0; j < 4; ++j) {
            pack[j]     = (short)f2b(o0[j]);
            pack[j + 4] = (short)f2b(o1[j]);
        }
        *(bf16x8*)(&sh.Xs[row * 264 + c8]) = pack;
    }
    __syncthreads();

    // ---- layer 1: M=64, N=512, K=256
    f32x4 zero4 = {0.f, 0.f, 0.f, 0.f};
    f32x4 acc1[4][8];
    #pragma unroll
    for (int rt = 0; rt < 4; ++rt)
        #pragma unroll
        for (int cw = 0; cw < 8; ++cw) acc1[rt][cw] = zero4;

    const unsigned short* bB = W1T + (wave * 128 + ln) * FIN + quad * 8;
    #pragma unroll
    for (int ks = 0; ks < 8; ++ks) {
        bf16x8 a[4], b[8];
        #pragma unroll
        for (int rt = 0; rt < 4; ++rt)
            a[rt] = *(const bf16x8*)(&sh.Xs[(rt * 16 + ln) * 264 + quad * 8 + ks * 32]);
        #pragma unroll
        for (int cw = 0; cw < 8; ++cw)
            b[cw] = *(const bf16x8*)(bB + cw * 16 * FIN + ks * 32);
        #pragma unroll
        for (int rt = 0; rt < 4; ++rt)
            #pragma unroll
            for (int cw = 0; cw < 8; ++cw)
                acc1[rt][cw] = mfma16(a[rt], b[cw], acc1[rt][cw]);
    }
    __syncthreads();   // done reading Xs before overwriting Hs

    // bias + relu -> bf16 -> swizzled LDS
    #pragma unroll
    for (int cw = 0; cw < 8; ++cw) {
        const int n = wave * 128 + cw * 16 + ln;
        const float bias = b1[n];
        #pragma unroll
        for (int rt = 0; rt < 4; ++rt)
            #pragma unroll
            for (int r = 0; r < 4; ++r) {
                const int row = rt * 16 + quad * 4 + r;
                const float v = fmaxf(acc1[rt][cw][r] + bias, 0.f);
                sh.Hs[(row << 9) + (((n >> 3) ^ (row & 7)) << 3) + (n & 7)] = f2b(v);
            }
    }
    __syncthreads();

    // ---- layer 2: M=64, N=256, K=512
    f32x4 acc2[4][4];
    #pragma unroll
    for (int rt = 0; rt < 4; ++rt)
        #pragma unroll
        for (int cw = 0; cw < 4; ++cw) acc2[rt][cw] = zero4;

    #pragma unroll
    for (int ks = 0; ks < 16; ++ks) {
        const int kb = ks * 4 + quad;
        bf16x8 a[4], b[4];
        #pragma unroll
        for (int rt = 0; rt < 4; ++rt) {
            const int row = rt * 16 + ln;
            a[rt] = *(const bf16x8*)(&sh.Hs[(row << 9) + (((kb ^ (row & 7)) << 3))]);
        }
        #pragma unroll
        for (int cw = 0; cw < 4; ++cw)
            b[cw] = *(const bf16x8*)(W2T + (wave * 64 + cw * 16 + ln) * FH + kb * 8);
        #pragma unroll
        for (int rt = 0; rt < 4; ++rt)
            #pragma unroll
            for (int cw = 0; cw < 4; ++cw)
                acc2[rt][cw] = mfma16(a[rt], b[cw], acc2[rt][cw]);
    }
    __syncthreads();   // done reading Hs before overwriting Msg

    // ---- epilogue 1: msg = relu(node_feat[src] + E) -> LDS (fp32)
    float biasv[4];
    #pragma unroll
    for (int cw = 0; cw < 4; ++cw)
        biasv[cw] = b2[wave * 64 + cw * 16 + ln];
    #pragma unroll
    for (int rt = 0; rt < 4; ++rt)
        #pragma unroll
        for (int r = 0; r < 4; ++r) {
            const int row = rt * 16 + quad * 4 + r;
            const int sn = snS[row];
            const float* nf = node_feat + (size_t)sn * FIN + wave * 64 + ln;
            #pragma unroll
            for (int cw = 0; cw < 4; ++cw) {
                const float e = acc2[rt][cw][r] + biasv[cw];
                sh.Msg[row * 260 + wave * 64 + cw * 16 + ln] =
                    fmaxf(nf[cw * 16] + e, 0.f);
            }
        }
    __syncthreads();

    // ---- epilogue 2: per-column run-length reduce over sorted dst rows.
    // dnS[row] is wave-uniform -> no divergence; Msg col reads are 2-way
    // bank-aliased (free).
    {
        const int col = tid;
        float run = sh.Msg[col];
        int cur = dnS[0];
        #pragma unroll 4
        for (int row = 1; row < 64; ++row) {
            const int d = dnS[row];
            if (d != cur) {
                atomicAdd(&out_h[(size_t)cur * FIN + col], run);
                run = 0.f;
                cur = d;
            }
            run += sh.Msg[row * 260 + col];
        }
        atomicAdd(&out_h[(size_t)cur * FIN + col], run);
    }
}

// ---------------------------------------------------------------- node MLP
__global__ void __launch_bounds__(256, 2)
gine_node(const float* __restrict__ node_feat,
          const float* __restrict__ out_h,
          const unsigned short* __restrict__ W1T,   // [512,256] bf16
          const float* __restrict__ b1,
          const unsigned short* __restrict__ W2T,   // [256,512] bf16
          const float* __restrict__ b2,
          const float* __restrict__ eps,
          float* __restrict__ out)
{
    __shared__ union {
        unsigned short Xs[64 * 264];
        unsigned short Hs[64 * 512];
    } sh;

    const int tid  = threadIdx.x;
    const int wave = tid >> 6;
    const int lane = tid & 63;
    const int quad = lane >> 4;
    const int ln   = lane & 15;
    const int n0   = blockIdx.x * 64;
    const float epsv = 1.0f + eps[0];

    // stage x = (1+eps)*node_feat + out_h  -> bf16 LDS
    #pragma unroll
    for (int it = 0; it < 8; ++it) {
        const int chunk = tid + it * 256;
        const int row = chunk >> 5;
        const int c8  = (chunk & 31) << 3;
        const int g   = n0 + row;
        bf16x8 pack = {0, 0, 0, 0, 0, 0, 0, 0};
        if (g < NN) {
            const float* pn = node_feat + (size_t)g * FIN + c8;
            const float* ph = out_h + (size_t)g * FIN + c8;
            f32x4 n0v = *(const f32x4*)(pn);
            f32x4 n1v = *(const f32x4*)(pn + 4);
            f32x4 h0v = *(const f32x4*)(ph);
            f32x4 h1v = *(const f32x4*)(ph + 4);
            #pragma unroll
            for (int j = 0; j < 4; ++j) {
                pack[j]     = (short)f2b(epsv * n0v[j] + h0v[j]);
                pack[j + 4] = (short)f2b(epsv * n1v[j] + h1v[j]);
            }
        }
        *(bf16x8*)(&sh.Xs[row * 264 + c8]) = pack;
    }
    __syncthreads();

    // ---- layer 1
    f32x4 zero4 = {0.f, 0.f, 0.f, 0.f};
    f32x4 acc1[4][8];
    #pragma unroll
    for (int rt = 0; rt < 4; ++rt)
        #pragma unroll
        for (int cw = 0; cw < 8; ++cw) acc1[rt][cw] = zero4;

    const unsigned short* bB = W1T + (wave * 128 + ln) * FIN + quad * 8;
    #pragma unroll
    for (int ks = 0; ks < 8; ++ks) {
        bf16x8 a[4], b[8];
        #pragma unroll
        for (int rt = 0; rt < 4; ++rt)
            a[rt] = *(const bf16x8*)(&sh.Xs[(rt * 16 + ln) * 264 + quad * 8 + ks * 32]);
        #pragma unroll
        for (int cw = 0; cw < 8; ++cw)
            b[cw] = *(const bf16x8*)(bB + cw * 16 * FIN + ks * 32);
        #pragma unroll
        for (int rt = 0; rt < 4; ++rt)
            #pragma unroll
            for (int cw = 0; cw < 8; ++cw)
                acc1[rt][cw] = mfma16(a[rt], b[cw], acc1[rt][cw]);
    }
    __syncthreads();

    #pragma unroll
    for (int cw = 0; cw < 8; ++cw) {
        const int n = wave * 128 + cw * 16 + ln;
        const float bias = b1[n];
        #pragma unroll
        for (int rt = 0; rt < 4; ++rt)
            #pragma unroll
            for (int r = 0; r < 4; ++r) {
                const int row = rt * 16 + quad * 4 + r;
                const float v = fmaxf(acc1[rt][cw][r] + bias, 0.f);
                sh.Hs[(row << 9) + (((n >> 3) ^ (row & 7)) << 3) + (n & 7)] = f2b(v);
            }
    }
    __syncthreads();

    // ---- layer 2
    f32x4 acc2[4][4];
    #pragma unroll
    for (int rt = 0; rt < 4; ++rt)
        #pragma unroll
        for (int cw = 0; cw < 4; ++cw) acc2[rt][cw] = zero4;

    #pragma unroll
    for (int ks = 0; ks < 16; ++ks) {
        const int kb = ks * 4 + quad;
        bf16x8 a[4], b[4];
        #pragma unroll
        for (int rt = 0; rt < 4; ++rt) {
            const int row = rt * 16 + ln;
            a[rt] = *(const bf16x8*)(&sh.Hs[(row << 9) + (((kb ^ (row & 7)) << 3))]);
        }
        #pragma unroll
        for (int cw = 0; cw < 4; ++cw)
            b[cw] = *(const bf16x8*)(W2T + (wave * 64 + cw * 16 + ln) * FH + kb * 8);
        #pragma unroll
        for (int rt = 0; rt < 4; ++rt)
            #pragma unroll
            for (int cw = 0; cw < 4; ++cw)
                acc2[rt][cw] = mfma16(a[rt], b[cw], acc2[rt][cw]);
    }

    float biasv[4];
    #pragma unroll
    for (int cw = 0; cw < 4; ++cw)
        biasv[cw] = b2[wave * 64 + cw * 16 + ln];
    #pragma unroll
    for (int rt = 0; rt < 4; ++rt)
        #pragma unroll
        for (int r = 0; r < 4; ++r) {
            const int row = rt * 16 + quad * 4 + r;
            const int g = n0 + row;
            if (g < NN) {
                #pragma unroll
                for (int cw = 0; cw < 4; ++cw)
                    out[(size_t)g * FIN + wave * 64 + cw * 16 + ln] =
                        acc2[rt][cw][r] + biasv[cw];
            }
        }
}

// ---------------------------------------------------------------- launch
extern "C" void kernel_launch(void* const* d_in, const int* in_sizes, int n_in,
                              void* d_out, int out_size, void* d_ws, size_t ws_size,
                              hipStream_t stream) {
    const float* node_feat = (const float*)d_in[0];
    const float* edge_feat = (const float*)d_in[1];
    const int* srcI = (const int*)d_in[2];
    const int* dstI = (const int*)d_in[3];
    const float* We1 = (const float*)d_in[4];
    const float* be1 = (const float*)d_in[5];
    const float* We2 = (const float*)d_in[6];
    const float* be2 = (const float*)d_in[7];
    const float* Wn1 = (const float*)d_in[8];
    const float* bn1 = (const float*)d_in[9];
    const float* Wn2 = (const float*)d_in[10];
    const float* bn2 = (const float*)d_in[11];
    const float* eps = (const float*)d_in[12];

    char* ws = (char*)d_ws;
    float* out_h = (float*)ws;                                  // 20,480,000 B
    unsigned short* W1T  = (unsigned short*)(ws + 20480000);    // 256 KB each
    unsigned short* W2T  = W1T + 131072;
    unsigned short* Wn1T = W2T + 131072;
    unsigned short* Wn2T = Wn1T + 131072;
    int* cnt    = (int*)(ws + 20480000 + 4 * 262144);           // 80 KB
    int* cursor = cnt + NN;                                     // 80 KB
    int* perm   = cursor + NN;                                  // 1.25 MB

    hipMemsetAsync(out_h, 0, (size_t)NN * FIN * sizeof(float), stream);
    hipMemsetAsync(cnt, 0, NN * sizeof(int), stream);

    transpose_f32_bf16<<<128, 256, 0, stream>>>(We1, W1T, FIN, FH);
    transpose_f32_bf16<<<128, 256, 0, stream>>>(We2, W2T, FH, FIN);
    transpose_f32_bf16<<<128, 256, 0, stream>>>(Wn1, Wn1T, FIN, FH);
    transpose_f32_bf16<<<128, 256, 0, stream>>>(Wn2, Wn2T, FH, FIN);

    hist_dst<<<(NE + 255) / 256, 256, 0, stream>>>(dstI, cnt);
    scan_excl<<<1, 1024, 0, stream>>>(cnt, cursor);
    scatter_perm<<<(NE + 255) / 256, 256, 0, stream>>>(dstI, cursor, perm);

    gine_edge<<<NE / 64, 256, 0, stream>>>(edge_feat, node_feat, srcI, dstI,
                                           perm, W1T, be1, W2T, be2, out_h);
    gine_node<<<(NN + 63) / 64, 256, 0, stream>>>(node_feat, out_h, Wn1T, bn1,
                                                  Wn2T, bn2, eps, (float*)d_out);
}

// Round 4
// 944.117 us; speedup vs baseline: 1.1333x; 1.0065x over previous
//
#include <hip/hip_runtime.h>

#define NN  20000
#define NE  320000
#define FIN 256
#define FH  512

typedef __attribute__((ext_vector_type(8))) short bf16x8;
typedef __attribute__((ext_vector_type(4))) float f32x4;

static __device__ __forceinline__ unsigned short f2b(float f) {
    union { float f; unsigned int i; } v; v.f = f;
    return (unsigned short)((v.i + 0x7fffu + ((v.i >> 16) & 1u)) >> 16);
}
static __device__ __forceinline__ f32x4 mfma16(bf16x8 a, bf16x8 b, f32x4 c) {
    return __builtin_amdgcn_mfma_f32_16x16x32_bf16(a, b, c, 0, 0, 0);
}

// ------------------------------------------------- all-weights transpose+cvt
// 512 blocks: 128 tiles of 32x32 per matrix. dst[c*R+r] = bf16(src[r*C+c]).
__global__ void prep_weights(const float* __restrict__ We1, const float* __restrict__ We2,
                             const float* __restrict__ Wn1, const float* __restrict__ Wn2,
                             unsigned short* __restrict__ W1T, unsigned short* __restrict__ W2T,
                             unsigned short* __restrict__ Wn1T, unsigned short* __restrict__ Wn2T) {
    const int m = blockIdx.x >> 7;
    const int t = blockIdx.x & 127;
    const float* src; unsigned short* dst; int R, C;
    if      (m == 0) { src = We1; dst = W1T;  R = 256; C = 512; }
    else if (m == 1) { src = We2; dst = W2T;  R = 512; C = 256; }
    else if (m == 2) { src = Wn1; dst = Wn1T; R = 256; C = 512; }
    else             { src = Wn2; dst = Wn2T; R = 512; C = 256; }
    __shared__ unsigned short tl[32][33];
    const int tx  = threadIdx.x & 31;
    const int tyb = threadIdx.x >> 5;
    const int cb = C >> 5;
    const int bx = t % cb, by = t / cb;
    #pragma unroll
    for (int j = 0; j < 4; ++j)
        tl[tyb * 4 + j][tx] = f2b(src[(size_t)(by * 32 + tyb * 4 + j) * C + bx * 32 + tx]);
    __syncthreads();
    #pragma unroll
    for (int j = 0; j < 4; ++j)
        dst[(size_t)(bx * 32 + tyb * 4 + j) * R + by * 32 + tx] = tl[tx][tyb * 4 + j];
}

// ------------------------------------------------- sort-by-dst prep
__global__ void hist_dst(const int* __restrict__ dstI, int* __restrict__ cnt) {
    int e = blockIdx.x * 256 + threadIdx.x;
    if (e < NE) atomicAdd(&cnt[dstI[e]], 1);
}

// single block, 1024 threads: exclusive prefix sum of cnt[NN] -> cursor[NN]
__global__ void scan_excl(const int* __restrict__ cnt, int* __restrict__ cursor) {
    __shared__ int s[1024];
    const int t = threadIdx.x;
    const int lo = t * 20;
    const int hi = (lo + 20 < NN) ? lo + 20 : NN;
    int sum = 0;
    for (int i = lo; i < hi; ++i) sum += cnt[i];
    s[t] = sum;
    __syncthreads();
    for (int off = 1; off < 1024; off <<= 1) {
        int v = (t >= off) ? s[t - off] : 0;
        __syncthreads();
        s[t] += v;
        __syncthreads();
    }
    int base = (t > 0) ? s[t - 1] : 0;
    for (int i = lo; i < hi; ++i) { cursor[i] = base; base += cnt[i]; }
}

__global__ void scatter_perm(const int* __restrict__ dstI,
                             int* __restrict__ cursor, int* __restrict__ perm) {
    int e = blockIdx.x * 256 + threadIdx.x;
    if (e < NE) {
        int pos = atomicAdd(&cursor[dstI[e]], 1);
        perm[pos] = e;
    }
}

// ---------------------------------------------------------------- edge MLP
// per block: 64 dst-sorted edges (via perm, XCD-swizzled so each XCD owns a
// contiguous sorted range -> out_h slice fits its 4MB L2). Interior dsts are
// block-exclusive -> plain stores; only the 2 boundary dsts use atomics.
__global__ void __launch_bounds__(256, 2)
gine_edge(const float* __restrict__ edge_feat,
          const float* __restrict__ node_feat,
          const int* __restrict__ srcI,
          const int* __restrict__ dstI,
          const int* __restrict__ perm,
          const unsigned short* __restrict__ W1T,   // [512,256] bf16 k-contig
          const float* __restrict__ b1,             // [512]
          const unsigned short* __restrict__ W2T,   // [256,512] bf16 k-contig
          const float* __restrict__ b2,             // [256]
          float* __restrict__ out_h)                // [NN,256] fp32 accum
{
    __shared__ union {
        unsigned short Xs[64 * 264];   // staged bf16 input, +8 pad
        unsigned short Hs[64 * 512];   // XOR-swizzled hidden
        float          Msg[64 * 260];  // fp32 messages, +4 pad
    } sh;
    __shared__ int snS[64], dnS[64], eS[64];

    const int tid  = threadIdx.x;
    const int wave = tid >> 6;
    const int lane = tid & 63;
    const int quad = lane >> 4;
    const int ln   = lane & 15;
    // XCD-affinity swizzle: 5000 blocks, round-robin b%8 -> XCD; give XCD k
    // the contiguous sorted chunk k*625..(k+1)*625-1.
    const int bs   = (blockIdx.x & 7) * 625 + (blockIdx.x >> 3);
    const int e0   = bs * 64;

    if (tid < 64) {
        const int e = perm[e0 + tid];
        eS[tid]  = e;
        snS[tid] = srcI[e];
        dnS[tid] = dstI[e];
    }
    __syncthreads();

    // ---- stage gathered edge_feat rows -> bf16 LDS
    #pragma unroll
    for (int it = 0; it < 8; ++it) {
        const int chunk = tid + it * 256;          // 2048 chunks of 8 elems
        const int row = chunk >> 5;
        const int c8  = (chunk & 31) << 3;
        const float* p = edge_feat + (size_t)eS[row] * FIN + c8;
        f32x4 o0 = *(const f32x4*)(p);
        f32x4 o1 = *(const f32x4*)(p + 4);
        bf16x8 pack;
        #pragma unroll
        for (int j = 0; j < 4; ++j) {
            pack[j]     = (short)f2b(o0[j]);
            pack[j + 4] = (short)f2b(o1[j]);
        }
        *(bf16x8*)(&sh.Xs[row * 264 + c8]) = pack;
    }
    __syncthreads();

    // ---- layer 1: M=64, N=512, K=256
    f32x4 zero4 = {0.f, 0.f, 0.f, 0.f};
    f32x4 acc1[4][8];
    #pragma unroll
    for (int rt = 0; rt < 4; ++rt)
        #pragma unroll
        for (int cw = 0; cw < 8; ++cw) acc1[rt][cw] = zero4;

    const unsigned short* bB = W1T + (wave * 128 + ln) * FIN + quad * 8;
    #pragma unroll
    for (int ks = 0; ks < 8; ++ks) {
        bf16x8 a[4], b[8];
        #pragma unroll
        for (int rt = 0; rt < 4; ++rt)
            a[rt] = *(const bf16x8*)(&sh.Xs[(rt * 16 + ln) * 264 + quad * 8 + ks * 32]);
        #pragma unroll
        for (int cw = 0; cw < 8; ++cw)
            b[cw] = *(const bf16x8*)(bB + cw * 16 * FIN + ks * 32);
        #pragma unroll
        for (int rt = 0; rt < 4; ++rt)
            #pragma unroll
            for (int cw = 0; cw < 8; ++cw)
                acc1[rt][cw] = mfma16(a[rt], b[cw], acc1[rt][cw]);
    }
    __syncthreads();   // done reading Xs before overwriting Hs

    // bias + relu -> bf16 -> swizzled LDS
    #pragma unroll
    for (int cw = 0; cw < 8; ++cw) {
        const int n = wave * 128 + cw * 16 + ln;
        const float bias = b1[n];
        #pragma unroll
        for (int rt = 0; rt < 4; ++rt)
            #pragma unroll
            for (int r = 0; r < 4; ++r) {
                const int row = rt * 16 + quad * 4 + r;
                const float v = fmaxf(acc1[rt][cw][r] + bias, 0.f);
                sh.Hs[(row << 9) + (((n >> 3) ^ (row & 7)) << 3) + (n & 7)] = f2b(v);
            }
    }
    __syncthreads();

    // ---- layer 2: M=64, N=256, K=512
    f32x4 acc2[4][4];
    #pragma unroll
    for (int rt = 0; rt < 4; ++rt)
        #pragma unroll
        for (int cw = 0; cw < 4; ++cw) acc2[rt][cw] = zero4;

    #pragma unroll
    for (int ks = 0; ks < 16; ++ks) {
        const int kb = ks * 4 + quad;
        bf16x8 a[4], b[4];
        #pragma unroll
        for (int rt = 0; rt < 4; ++rt) {
            const int row = rt * 16 + ln;
            a[rt] = *(const bf16x8*)(&sh.Hs[(row << 9) + (((kb ^ (row & 7)) << 3))]);
        }
        #pragma unroll
        for (int cw = 0; cw < 4; ++cw)
            b[cw] = *(const bf16x8*)(W2T + (wave * 64 + cw * 16 + ln) * FH + kb * 8);
        #pragma unroll
        for (int rt = 0; rt < 4; ++rt)
            #pragma unroll
            for (int cw = 0; cw < 4; ++cw)
                acc2[rt][cw] = mfma16(a[rt], b[cw], acc2[rt][cw]);
    }
    __syncthreads();   // done reading Hs before overwriting Msg

    // ---- epilogue 1: msg = relu(node_feat[src] + E) -> LDS (fp32)
    float biasv[4];
    #pragma unroll
    for (int cw = 0; cw < 4; ++cw)
        biasv[cw] = b2[wave * 64 + cw * 16 + ln];
    #pragma unroll
    for (int rt = 0; rt < 4; ++rt)
        #pragma unroll
        for (int r = 0; r < 4; ++r) {
            const int row = rt * 16 + quad * 4 + r;
            const int sn = snS[row];
            const float* nf = node_feat + (size_t)sn * FIN + wave * 64 + ln;
            #pragma unroll
            for (int cw = 0; cw < 4; ++cw) {
                const float e = acc2[rt][cw][r] + biasv[cw];
                sh.Msg[row * 260 + wave * 64 + cw * 16 + ln] =
                    fmaxf(nf[cw * 16] + e, 0.f);
            }
        }
    __syncthreads();

    // ---- epilogue 2: run-length reduce over sorted dst rows.
    // Interior dst (!= dnS[0] and != dnS[63]) is exclusively owned by this
    // block (sorted) -> plain store. Boundary dsts -> atomicAdd.
    {
        const int col = tid;
        const int d0 = dnS[0], d63 = dnS[63];
        float run = sh.Msg[col];
        int cur = d0;
        #pragma unroll 4
        for (int row = 1; row < 64; ++row) {
            const int d = dnS[row];
            if (d != cur) {
                if (cur == d0 || cur == d63)
                    atomicAdd(&out_h[(size_t)cur * FIN + col], run);
                else
                    out_h[(size_t)cur * FIN + col] = run;
                run = 0.f;
                cur = d;
            }
            run += sh.Msg[row * 260 + col];
        }
        atomicAdd(&out_h[(size_t)cur * FIN + col], run);   // cur == d63
    }
}

// ---------------------------------------------------------------- node MLP
__global__ void __launch_bounds__(256, 2)
gine_node(const float* __restrict__ node_feat,
          const float* __restrict__ out_h,
          const unsigned short* __restrict__ W1T,   // [512,256] bf16
          const float* __restrict__ b1,
          const unsigned short* __restrict__ W2T,   // [256,512] bf16
          const float* __restrict__ b2,
          const float* __restrict__ eps,
          float* __restrict__ out)
{
    __shared__ union {
        unsigned short Xs[64 * 264];
        unsigned short Hs[64 * 512];
    } sh;

    const int tid  = threadIdx.x;
    const int wave = tid >> 6;
    const int lane = tid & 63;
    const int quad = lane >> 4;
    const int ln   = lane & 15;
    const int n0   = blockIdx.x * 64;
    const float epsv = 1.0f + eps[0];

    // stage x = (1+eps)*node_feat + out_h  -> bf16 LDS
    #pragma unroll
    for (int it = 0; it < 8; ++it) {
        const int chunk = tid + it * 256;
        const int row = chunk >> 5;
        const int c8  = (chunk & 31) << 3;
        const int g   = n0 + row;
        bf16x8 pack = {0, 0, 0, 0, 0, 0, 0, 0};
        if (g < NN) {
            const float* pn = node_feat + (size_t)g * FIN + c8;
            const float* ph = out_h + (size_t)g * FIN + c8;
            f32x4 n0v = *(const f32x4*)(pn);
            f32x4 n1v = *(const f32x4*)(pn + 4);
            f32x4 h0v = *(const f32x4*)(ph);
            f32x4 h1v = *(const f32x4*)(ph + 4);
            #pragma unroll
            for (int j = 0; j < 4; ++j) {
                pack[j]     = (short)f2b(epsv * n0v[j] + h0v[j]);
                pack[j + 4] = (short)f2b(epsv * n1v[j] + h1v[j]);
            }
        }
        *(bf16x8*)(&sh.Xs[row * 264 + c8]) = pack;
    }
    __syncthreads();

    // ---- layer 1
    f32x4 zero4 = {0.f, 0.f, 0.f, 0.f};
    f32x4 acc1[4][8];
    #pragma unroll
    for (int rt = 0; rt < 4; ++rt)
        #pragma unroll
        for (int cw = 0; cw < 8; ++cw) acc1[rt][cw] = zero4;

    const unsigned short* bB = W1T + (wave * 128 + ln) * FIN + quad * 8;
    #pragma unroll
    for (int ks = 0; ks < 8; ++ks) {
        bf16x8 a[4], b[8];
        #pragma unroll
        for (int rt = 0; rt < 4; ++rt)
            a[rt] = *(const bf16x8*)(&sh.Xs[(rt * 16 + ln) * 264 + quad * 8 + ks * 32]);
        #pragma unroll
        for (int cw = 0; cw < 8; ++cw)
            b[cw] = *(const bf16x8*)(bB + cw * 16 * FIN + ks * 32);
        #pragma unroll
        for (int rt = 0; rt < 4; ++rt)
            #pragma unroll
            for (int cw = 0; cw < 8; ++cw)
                acc1[rt][cw] = mfma16(a[rt], b[cw], acc1[rt][cw]);
    }
    __syncthreads();

    #pragma unroll
    for (int cw = 0; cw < 8; ++cw) {
        const int n = wave * 128 + cw * 16 + ln;
        const float bias = b1[n];
        #pragma unroll
        for (int rt = 0; rt < 4; ++rt)
            #pragma unroll
            for (int r = 0; r < 4; ++r) {
                const int row = rt * 16 + quad * 4 + r;
                const float v = fmaxf(acc1[rt][cw][r] + bias, 0.f);
                sh.Hs[(row << 9) + (((n >> 3) ^ (row & 7)) << 3) + (n & 7)] = f2b(v);
            }
    }
    __syncthreads();

    // ---- layer 2
    f32x4 acc2[4][4];
    #pragma unroll
    for (int rt = 0; rt < 4; ++rt)
        #pragma unroll
        for (int cw = 0; cw < 4; ++cw) acc2[rt][cw] = zero4;

    #pragma unroll
    for (int ks = 0; ks < 16; ++ks) {
        const int kb = ks * 4 + quad;
        bf16x8 a[4], b[4];
        #pragma unroll
        for (int rt = 0; rt < 4; ++rt) {
            const int row = rt * 16 + ln;
            a[rt] = *(const bf16x8*)(&sh.Hs[(row << 9) + (((kb ^ (row & 7)) << 3))]);
        }
        #pragma unroll
        for (int cw = 0; cw < 4; ++cw)
            b[cw] = *(const bf16x8*)(W2T + (wave * 64 + cw * 16 + ln) * FH + kb * 8);
        #pragma unroll
        for (int rt = 0; rt < 4; ++rt)
            #pragma unroll
            for (int cw = 0; cw < 4; ++cw)
                acc2[rt][cw] = mfma16(a[rt], b[cw], acc2[rt][cw]);
    }

    float biasv[4];
    #pragma unroll
    for (int cw = 0; cw < 4; ++cw)
        biasv[cw] = b2[wave * 64 + cw * 16 + ln];
    #pragma unroll
    for (int rt = 0; rt < 4; ++rt)
        #pragma unroll
        for (int r = 0; r < 4; ++r) {
            const int row = rt * 16 + quad * 4 + r;
            const int g = n0 + row;
            if (g < NN) {
                #pragma unroll
                for (int cw = 0; cw < 4; ++cw)
                    out[(size_t)g * FIN + wave * 64 + cw * 16 + ln] =
                        acc2[rt][cw][r] + biasv[cw];
            }
        }
}

// ---------------------------------------------------------------- launch
extern "C" void kernel_launch(void* const* d_in, const int* in_sizes, int n_in,
                              void* d_out, int out_size, void* d_ws, size_t ws_size,
                              hipStream_t stream) {
    const float* node_feat = (const float*)d_in[0];
    const float* edge_feat = (const float*)d_in[1];
    const int* srcI = (const int*)d_in[2];
    const int* dstI = (const int*)d_in[3];
    const float* We1 = (const float*)d_in[4];
    const float* be1 = (const float*)d_in[5];
    const float* We2 = (const float*)d_in[6];
    const float* be2 = (const float*)d_in[7];
    const float* Wn1 = (const float*)d_in[8];
    const float* bn1 = (const float*)d_in[9];
    const float* Wn2 = (const float*)d_in[10];
    const float* bn2 = (const float*)d_in[11];
    const float* eps = (const float*)d_in[12];

    char* ws = (char*)d_ws;
    float* out_h = (float*)ws;                                  // 20,480,000 B
    unsigned short* W1T  = (unsigned short*)(ws + 20480000);    // 256 KB each
    unsigned short* W2T  = W1T + 131072;
    unsigned short* Wn1T = W2T + 131072;
    unsigned short* Wn2T = Wn1T + 131072;
    int* cnt    = (int*)(ws + 20480000 + 4 * 262144);           // 80 KB
    int* cursor = cnt + NN;                                     // 80 KB
    int* perm   = cursor + NN;                                  // 1.25 MB

    hipMemsetAsync(out_h, 0, (size_t)NN * FIN * sizeof(float), stream);
    hipMemsetAsync(cnt, 0, NN * sizeof(int), stream);

    prep_weights<<<512, 256, 0, stream>>>(We1, We2, Wn1, Wn2, W1T, W2T, Wn1T, Wn2T);

    hist_dst<<<(NE + 255) / 256, 256, 0, stream>>>(dstI, cnt);
    scan_excl<<<1, 1024, 0, stream>>>(cnt, cursor);
    scatter_perm<<<(NE + 255) / 256, 256, 0, stream>>>(dstI, cursor, perm);

    gine_edge<<<NE / 64, 256, 0, stream>>>(edge_feat, node_feat, srcI, dstI,
                                           perm, W1T, be1, W2T, be2, out_h);
    gine_node<<<(NN + 63) / 64, 256, 0, stream>>>(node_feat, out_h, Wn1T, bn1,
                                                  Wn2T, bn2, eps, (float*)d_out);
}